// Round 4
// 1323.904 us; speedup vs baseline: 1.0434x; 1.0434x over previous
//
#include <hip/hip_runtime.h>
#include <stdint.h>

// BitLinear on MI355X: per-token int8 activation quant + per-tensor ternary
// weight quant + exact int8 MFMA GEMM.
//
// GEMM: 256x256 tile, 8 waves, quad-buffered K-tiles (KT=64), counted-vmcnt
// phase pipeline (never vmcnt(0) in main loop), LDS XOR swizzle via
// pre-swizzled global source (global_load_lds writes linearly), s_setprio
// around MFMA clusters, XCD-aware block swizzle.

typedef int v4i __attribute__((ext_vector_type(4)));

#define QEPS 1e-5f

#define M_DIM 8192
#define N_DIM 16384
#define K_DIM 4096

// ---------------- Kernel 1: sum of |w| (double accumulate) ----------------
__global__ void wabs_sum(const float* __restrict__ w, double* __restrict__ acc,
                         int n4) {
    int idx = blockIdx.x * blockDim.x + threadIdx.x;
    int stride = gridDim.x * blockDim.x;
    const float4* w4 = (const float4*)w;
    double s = 0.0;
    for (int i = idx; i < n4; i += stride) {
        float4 v = w4[i];
        s += (double)(fabsf(v.x) + fabsf(v.y) + fabsf(v.z) + fabsf(v.w));
    }
    #pragma unroll
    for (int off = 32; off > 0; off >>= 1)
        s += __shfl_down(s, off, 64);
    __shared__ double sm[4];
    int lane = threadIdx.x & 63, wv = threadIdx.x >> 6;
    if (lane == 0) sm[wv] = s;
    __syncthreads();
    if (threadIdx.x == 0) {
        atomicAdd(acc, sm[0] + sm[1] + sm[2] + sm[3]);
    }
}

// ---------------- Kernel 2: ternary weight quant ----------------
__device__ __forceinline__ int tq1(float v, float s) {
    float q = rintf(v * s);
    q = fminf(fmaxf(q, -1.0f), 1.0f);
    return (int)q;
}

__global__ void wquant(const float* __restrict__ w, int8_t* __restrict__ tw,
                       const double* __restrict__ acc, double inv_cnt, int n4) {
    double mean = (*acc) * inv_cnt;
    float mclip = (float)fmax(mean, (double)QEPS);
    float sw = 1.0f / mclip;
    int idx = blockIdx.x * blockDim.x + threadIdx.x;
    int stride = gridDim.x * blockDim.x;
    const float4* w4 = (const float4*)w;
    uint32_t* out = (uint32_t*)tw;
    for (int i = idx; i < n4; i += stride) {
        float4 v = w4[i];
        uint32_t a = (uint32_t)(tq1(v.x, sw) & 0xff);
        uint32_t b = (uint32_t)(tq1(v.y, sw) & 0xff);
        uint32_t c = (uint32_t)(tq1(v.z, sw) & 0xff);
        uint32_t d = (uint32_t)(tq1(v.w, sw) & 0xff);
        out[i] = a | (b << 8) | (c << 16) | (d << 24);
    }
}

// ---------------- Kernel 3: per-token int8 activation quant ----------------
__device__ __forceinline__ int q8(float v, float s) {
    float q = rintf(v * s);
    q = fminf(fmaxf(q, -128.0f), 127.0f);
    return (int)q;
}

__global__ void xquant(const float* __restrict__ x, int8_t* __restrict__ qx,
                       float* __restrict__ rowscale) {
    int row = blockIdx.x;
    int t = threadIdx.x;
    const float4* xr = (const float4*)(x + (size_t)row * K_DIM);
    float4 v[4];
    float m = 0.0f;
    #pragma unroll
    for (int i = 0; i < 4; i++) {
        v[i] = xr[t + i * 256];
        m = fmaxf(m, fmaxf(fmaxf(fabsf(v[i].x), fabsf(v[i].y)),
                           fmaxf(fabsf(v[i].z), fabsf(v[i].w))));
    }
    #pragma unroll
    for (int off = 32; off > 0; off >>= 1)
        m = fmaxf(m, __shfl_down(m, off, 64));
    __shared__ float sm[4];
    int lane = t & 63, wv = t >> 6;
    if (lane == 0) sm[wv] = m;
    __syncthreads();
    m = fmaxf(fmaxf(sm[0], sm[1]), fmaxf(sm[2], sm[3]));
    float mc = fmaxf(m, QEPS);
    float scale = 127.0f / mc;
    if (t == 0) rowscale[row] = mc * (1.0f / 127.0f);
    uint32_t* qr = (uint32_t*)(qx + (size_t)row * K_DIM);
    #pragma unroll
    for (int i = 0; i < 4; i++) {
        uint32_t a = (uint32_t)(q8(v[i].x, scale) & 0xff);
        uint32_t b = (uint32_t)(q8(v[i].y, scale) & 0xff);
        uint32_t c = (uint32_t)(q8(v[i].z, scale) & 0xff);
        uint32_t d = (uint32_t)(q8(v[i].w, scale) & 0xff);
        qr[t + i * 256] = a | (b << 8) | (c << 16) | (d << 24);
    }
}

// ---------------- Kernel 4: int8 MFMA GEMM, 256^2 counted-vmcnt pipeline ---
// Geometry: BM=BN=256, KT=64 int8 per K-tile, NT=64 tiles. 512 threads =
// 8 waves (2M x 4N); per-wave output 128x64 = 8mi x 4ni fragments of
// mfma_i32_16x16x64_i8. LDS: 4 slots per operand (tile t -> slot t&3),
// slot = 256 rows x 64 B = 16 KB; total 128 KiB -> 1 block/CU.
//
// Schedule per tile t (2 phases):
//  PhA(t): ds_read b0,b1 + a[0..7] (slot t&3) | stage B(t+3) -> slot (t-1)&3
//          | setprio(1) 16 MFMA (ni0,1) setprio(0) | s_barrier
//  PhB(t): ds_read b2,b3 | stage A(t+4) -> slot t&3 | setprio(1) 16 MFMA
//          (ni2,3) setprio(0) | s_waitcnt vmcnt(10) | s_barrier
// vmcnt ledger (2 loads/event): event order A0,B0,A1,B1,A2,B2,A3,B3,A4,B4,...
// At PhB(t)'s wait, issued loads = 18+4t; vmcnt(10) completes the first
// 8+4t loads = first 2t+4 events = exactly through A(t+1),B(t+1) — the
// operands PhA(t+1) reads. Tail drains 8 -> 4 -> 0; vmcnt(63) = no-op.
// Slot-overwrite safety: each overwriting stage is issued after the barrier
// at which all waves have consumed that slot (ds_read results feed the same
// phase's MFMAs; compiler orders them via lgkmcnt before the barrier).
//
// LDS swizzle: read addr byte ^= ((row>>1)&3)<<4 -> each 8-lane phase of a
// ds_read_b128 hits 8 distinct 4-bank groups (conflict-free). Since
// global_load_lds writes base+lane*16 linearly, the same involution is
// applied to the global SOURCE column: srccol16 = (lane&3) ^ ((lane>>3)&3),
// which equals slot ^ ((row>>1)&3) for the row this lane's 16B lands in.

#define BM 256
#define BN 256
#define KT 64
#define SLOT 16384

__device__ __forceinline__ void async_copy16(const void* g, void* l) {
    __builtin_amdgcn_global_load_lds(
        (__attribute__((address_space(1))) void*)g,
        (__attribute__((address_space(3))) void*)l, 16, 0, 0);
}

#define WAITVM_IMM(N) asm volatile("s_waitcnt vmcnt(" #N ")" ::: "memory")
#define WAITVM(N) WAITVM_IMM(N)

__global__ __launch_bounds__(512, 2)
void gemm_i8(const int8_t* __restrict__ A,   // [M][K] int8
             const int8_t* __restrict__ B,   // [N][K] ternary int8
             const float* __restrict__ rowscale,
             const double* __restrict__ macc, double inv_cnt,
             float* __restrict__ C) {
    __shared__ int8_t As[4][SLOT];
    __shared__ int8_t Bs[4][SLOT];

    const int tid = threadIdx.x;
    const int wave = tid >> 6;
    const int lane = tid & 63;

    // XCD-aware bijective swizzle: 2048 blocks, 8 XCDs, 256 blocks each.
    // Within an XCD, bn varies fastest -> A-panel (1 MB) reused 64x in L2.
    const int orig = blockIdx.x;
    const int idx = (orig & 7) * 256 + (orig >> 3);
    const int bm = (idx >> 6) * BM;   // 32 block-rows
    const int bn = (idx & 63) * BN;   // 64 block-cols

    const int wr = wave >> 2;   // 0..1  (M side)
    const int wc = wave & 3;    // 0..3  (N side)
    const int fr = lane & 15;   // fragment row
    const int q  = lane >> 4;   // 16-byte quarter of K=64

    // swizzled ds_read base offsets ((row>>1)&3 == (fr>>1)&3 since fragment
    // row-bases are multiples of 16)
    const int sl   = (q ^ ((fr >> 1) & 3)) << 4;
    const int aoff = (wr * 128 + fr) * 64 + sl;  // + mi*1024
    const int boff = (wc * 64 + fr) * 64 + sl;   // + ni*1024

    // staging: per operand per tile, 2 issues/thread; chunk = issue*8+wave,
    // LDS linear L = chunk*1024 + lane*16 -> row = chunk*16 + (lane>>2),
    // pre-swizzled source column-slot = (lane&3) ^ ((lane>>3)&3)
    const int l2   = lane >> 2;
    const int gcol = ((lane & 3) ^ ((lane >> 3) & 3)) << 4;
    const int c0   = wave;
    const int c1   = 8 + wave;
    const int8_t* aS0 = A + (size_t)(bm + c0 * 16 + l2) * K_DIM + gcol;
    const int8_t* aS1 = A + (size_t)(bm + c1 * 16 + l2) * K_DIM + gcol;
    const int8_t* bS0 = B + (size_t)(bn + c0 * 16 + l2) * K_DIM + gcol;
    const int8_t* bS1 = B + (size_t)(bn + c1 * 16 + l2) * K_DIM + gcol;

    v4i acc[8][4] = {};
    v4i a[8];  // A fragments, live across PhA->PhB of each tile

#define STAGE_A(T) do { const int _s = (T) & 3; const int _k = (T) * KT;    \
        async_copy16(aS0 + _k, &As[_s][c0 * 1024]);                         \
        async_copy16(aS1 + _k, &As[_s][c1 * 1024]); } while (0)
#define STAGE_B(T) do { const int _s = (T) & 3; const int _k = (T) * KT;    \
        async_copy16(bS0 + _k, &Bs[_s][c0 * 1024]);                         \
        async_copy16(bS1 + _k, &Bs[_s][c1 * 1024]); } while (0)

#define PHASE_A(T, DOSTAGE) do {                                            \
        const int8_t* _as = As[(T) & 3];                                    \
        const int8_t* _bs = Bs[(T) & 3];                                    \
        v4i b0 = *(const v4i*)(_bs + boff);                                 \
        v4i b1 = *(const v4i*)(_bs + boff + 1024);                          \
        _Pragma("unroll")                                                   \
        for (int mi = 0; mi < 8; mi++)                                      \
            a[mi] = *(const v4i*)(_as + aoff + mi * 1024);                  \
        if (DOSTAGE) STAGE_B((T) + 3);                                      \
        __builtin_amdgcn_s_setprio(1);                                      \
        _Pragma("unroll")                                                   \
        for (int mi = 0; mi < 8; mi++)                                      \
            acc[mi][0] = __builtin_amdgcn_mfma_i32_16x16x64_i8(             \
                a[mi], b0, acc[mi][0], 0, 0, 0);                            \
        _Pragma("unroll")                                                   \
        for (int mi = 0; mi < 8; mi++)                                      \
            acc[mi][1] = __builtin_amdgcn_mfma_i32_16x16x64_i8(             \
                a[mi], b1, acc[mi][1], 0, 0, 0);                            \
        __builtin_amdgcn_s_setprio(0);                                      \
        __builtin_amdgcn_s_barrier();                                       \
    } while (0)

#define PHASE_B(T, DOSTAGE, VM) do {                                        \
        const int8_t* _bs = Bs[(T) & 3];                                    \
        v4i b2 = *(const v4i*)(_bs + boff + 2048);                          \
        v4i b3 = *(const v4i*)(_bs + boff + 3072);                          \
        if (DOSTAGE) STAGE_A((T) + 4);                                      \
        __builtin_amdgcn_s_setprio(1);                                      \
        _Pragma("unroll")                                                   \
        for (int mi = 0; mi < 8; mi++)                                      \
            acc[mi][2] = __builtin_amdgcn_mfma_i32_16x16x64_i8(             \
                a[mi], b2, acc[mi][2], 0, 0, 0);                            \
        _Pragma("unroll")                                                   \
        for (int mi = 0; mi < 8; mi++)                                      \
            acc[mi][3] = __builtin_amdgcn_mfma_i32_16x16x64_i8(             \
                a[mi], b3, acc[mi][3], 0, 0, 0);                            \
        __builtin_amdgcn_s_setprio(0);                                      \
        WAITVM(VM);                                                         \
        __builtin_amdgcn_s_barrier();                                       \
    } while (0)

    // Prologue: prime pipeline with 7 stage-events (A0,B0,A1,B1,A2,B2,A3);
    // vmcnt(10) completes A0,B0 (14 loads issued, keep 10 -> oldest 4 done).
    STAGE_A(0); STAGE_B(0); STAGE_A(1); STAGE_B(1);
    STAGE_A(2); STAGE_B(2); STAGE_A(3);
    WAITVM(10);
    __builtin_amdgcn_s_barrier();

    // Main loop: tiles 0..59 fully staged; unroll x4 keeps slot cycling.
    for (int t4 = 0; t4 < 60; t4 += 4) {
        PHASE_A(t4 + 0, 1); PHASE_B(t4 + 0, 1, 10);
        PHASE_A(t4 + 1, 1); PHASE_B(t4 + 1, 1, 10);
        PHASE_A(t4 + 2, 1); PHASE_B(t4 + 2, 1, 10);
        PHASE_A(t4 + 3, 1); PHASE_B(t4 + 3, 1, 10);
    }
    // Tail: tiles 60..63; vmcnt drains 8 -> 4 -> 0; vmcnt(63) = no-op.
    PHASE_A(60, 1); PHASE_B(60, 0, 8);
    PHASE_A(61, 0); PHASE_B(61, 0, 4);
    PHASE_A(62, 0); PHASE_B(62, 0, 0);
    PHASE_A(63, 0); PHASE_B(63, 0, 63);

    // Epilogue: C/D layout col=lane&15, row=(lane>>4)*4+reg.
    float mw = (float)fmax((*macc) * inv_cnt, (double)QEPS);
    const int col0 = bn + wc * 64 + fr;
    const int rb   = bm + wr * 128 + q * 4;
    #pragma unroll
    for (int mi = 0; mi < 8; mi++) {
        #pragma unroll
        for (int r = 0; r < 4; r++) {
            const int row = rb + mi * 16 + r;
            const float rs = rowscale[row] * mw;
            float* crow = C + (size_t)row * N_DIM;
            #pragma unroll
            for (int ni = 0; ni < 4; ni++) {
                crow[col0 + ni * 16] = (float)acc[mi][ni][r] * rs;
            }
        }
    }
}

// ---------------- launch ----------------
extern "C" void kernel_launch(void* const* d_in, const int* in_sizes, int n_in,
                              void* d_out, int out_size, void* d_ws,
                              size_t ws_size, hipStream_t stream) {
    const float* x = (const float*)d_in[0];
    const float* w = (const float*)d_in[1];
    float* out = (float*)d_out;

    const size_t QX_BYTES = (size_t)M_DIM * K_DIM;        // 33554432
    const size_t TW_BYTES = (size_t)N_DIM * K_DIM;        // 67108864
    int8_t* qx = (int8_t*)d_ws;
    int8_t* tw = (int8_t*)d_ws + QX_BYTES;
    float* rowscale = (float*)((char*)d_ws + QX_BYTES + TW_BYTES);
    double* macc = (double*)((char*)d_ws + QX_BYTES + TW_BYTES +
                             (size_t)M_DIM * sizeof(float));

    const double inv_cnt = 1.0 / (double)((size_t)N_DIM * K_DIM);

    (void)hipMemsetAsync(macc, 0, sizeof(double), stream);
    wabs_sum<<<1024, 256, 0, stream>>>(w, macc, (N_DIM * K_DIM) / 4);
    wquant<<<2048, 256, 0, stream>>>(w, tw, macc, inv_cnt, (N_DIM * K_DIM) / 4);
    xquant<<<M_DIM, 256, 0, stream>>>(x, qx, rowscale);
    gemm_i8<<<2048, 512, 0, stream>>>(qx, tw, rowscale, macc, inv_cnt, out);
}